// Round 8
// baseline (336.565 us; speedup 1.0000x reference)
//
#include <hip/hip_runtime.h>
#include <hip/hip_cooperative_groups.h>
#include <cstdint>
#include <cstddef>

namespace cg = cooperative_groups;

// Problem constants (from reference)
#define B_SZ   512
#define DIN    256
#define DOUT   256
#define KNOTS  64
#define NK     63                 // intervals = KNOTS-1
#define HSTEP  (4.0f / 63.0f)
#define INV_H  15.75f             // exact in f32

// XCD-affine slicing of the input dimension
#define NSLICE 8                  // = number of XCDs
#define ISLICE (DIN / NSLICE)     // 32 input dims -> 3.94 MiB table slice per XCD
#define OCW    64                 // o-chunk width per build block
#define LSTR   67                 // LDS row stride (floats): 67%32=3 -> 2-way banks (free)

typedef _Float16 h2f __attribute__((ext_vector_type(2)));

// Per-interval table entry: {y0, y1-y0, h*m0, h*m1} as 4 x f16 = 8 B.
struct __align__(8) Ent { h2f ydy; h2f hmm; };

// Per-(b,i) record: table byte offset + hermite weights {1,h01} {h10,h11}.
struct __align__(16) Rec { int off; h2f w01; h2f w23; int pad; };

static_assert(sizeof(Ent) == 8,  "Ent must be 8 bytes");
static_assert(sizeof(Rec) == 16, "Rec must be 16 bytes");

#if defined(__has_builtin)
#  if __has_builtin(__builtin_amdgcn_fdot2)
#    define HAVE_FDOT2 1
#  endif
#endif

static __device__ __forceinline__ float dot2acc(h2f a, h2f b, float acc) {
#ifdef HAVE_FDOT2
    return __builtin_amdgcn_fdot2(a, b, acc, false);
#else
    return acc + (float)a.x * (float)b.x + (float)a.y * (float)b.y;
#endif
}

// ---- PCHIP slope helpers (reference semantics, f32 exact) ----
static __device__ __forceinline__ float pchip_edge(float dA, float dB) {
    float m = 0.5f * (3.0f * dA - dB);
    if (m * dA <= 0.0f) {
        m = 0.0f;
    } else if (dA * dB < 0.0f && fabsf(m) > 3.0f * fabsf(dA)) {
        m = 3.0f * dA;
    }
    return m;
}

static __device__ __forceinline__ float pchip_inner(float d0, float d1) {
    if (d0 * d1 > 0.0f) {
        float denom = d0 + d1;
        if (fabsf(denom) < 1e-12f) return 0.0f;
        return 2.0f * d0 * d1 / denom;
    }
    return 0.0f;
}

// ---- Build phase (identical math to round-7 build_coef) ----
// Grid 1024 = 256 i x 4 o-chunks; bid&7 = slice(i) -> lines born in the XCD L2
// that the forward phase (slice = bid&7) reads them from.
static __device__ __forceinline__ void build_phase(const float* __restrict__ y,
                                                   Ent* __restrict__ C,
                                                   const float* __restrict__ bias,
                                                   float* __restrict__ out) {
    __shared__ float ly[OCW * LSTR];      // 17,152 B

    const int bid   = blockIdx.x;
    const int slice = bid & 7;
    const int jdim  = (bid >> 3) & 31;
    const int i     = slice * ISLICE + jdim;   // input dim, XCD-affine
    const int oc    = bid >> 8;                // o-chunk 0..3
    const int o0    = oc * OCW;
    const int t     = threadIdx.x;

    // out = bias init: first 256 blocks write one float2 per thread.
    if (bid < 256) {
        int t2 = bid * 256 + t;
        int ob = (t * 2) & (DOUT - 1);
        float2 bv;
        bv.x = bias[ob];
        bv.y = bias[ob + 1];
        ((float2*)out)[t2] = bv;
    }

    // Phase A: coalesced stage of 64 rows x 64 knots (16 KB contiguous).
    const float4* src = (const float4*)(y + ((size_t)i * DOUT + o0) * KNOTS);
#pragma unroll
    for (int z = 0; z < 4; ++z) {
        int f = t + 256 * z;
        float4 v = src[f];
        int row = f >> 4;
        int kq  = (f & 15) * 4;
        float* dst = &ly[row * LSTR + kq];
        dst[0] = v.x; dst[1] = v.y; dst[2] = v.z; dst[3] = v.w;
    }
    __syncthreads();

    // Phase B: 4 threads/row, 15-16 entries each from a 19-float halo window.
    const int r  = t >> 2;
    const int q  = t & 3;
    const int k0 = q * 16;
    const int o  = o0 + r;
    const float* rowp = &ly[r * LSTR];

    float ys[19];
#pragma unroll
    for (int u = 0; u < 19; ++u) {
        int kk = k0 - 1 + u;
        kk = kk < 0 ? 0 : (kk > KNOTS - 1 ? KNOTS - 1 : kk);
        ys[u] = rowp[kk];
    }
    float dd[18];
#pragma unroll
    for (int u = 0; u < 18; ++u) dd[u] = (ys[u + 1] - ys[u]) * INV_H;

    const int cnt = (q == 3) ? 15 : 16;
    Ent* outp = C + ((size_t)i * NK + k0) * DOUT + o;
#pragma unroll
    for (int n = 0; n < 16; ++n) {
        if (n < cnt) {
            const int k   = k0 + n;
            float d_m1 = dd[n];
            float d_0  = dd[n + 1];
            float d_p1 = dd[n + 2];
            float mk  = pchip_inner(d_m1, d_0);
            if (k == 0)      mk  = pchip_edge(d_0, d_p1);
            float mk1 = pchip_inner(d_0, d_p1);
            if (k == NK - 1) mk1 = pchip_edge(d_0, d_m1);
            float y0 = ys[n + 1];
            float y1 = ys[n + 2];
            Ent e;
            e.ydy.x = (_Float16)y0;
            e.ydy.y = (_Float16)(y1 - y0);
            e.hmm.x = (_Float16)(HSTEP * mk);
            e.hmm.y = (_Float16)(HSTEP * mk1);
            outp[(size_t)n * DOUT] = e;
        }
    }
}

// ---- Forward phase (identical math to round-6 kan_forward) ----
// Grid 1024 = 8 slices x 128 sample-chunks of 4; 256 threads = one o each;
// thread does 4 samples x 32 terms, one atomicAdd per sample.
static __device__ __forceinline__ void forward_phase(const float* __restrict__ x,
                                                     const Ent* __restrict__ C,
                                                     float* __restrict__ out) {
    __shared__ Rec recs[4 * ISLICE];      // 128 records x 16 B = 2 KB

    const int bid   = blockIdx.x;
    const int slice = bid & (NSLICE - 1);
    const int chunk = bid >> 3;           // 0..127
    const int t     = threadIdx.x;

    if (t < 4 * ISLICE) {                 // 128 threads stage the records
        const int s = t >> 5;
        const int j = t & (ISLICE - 1);
        const int b = chunk * 4 + s;
        const int i = slice * ISLICE + j;
        float xv = x[b * DIN + i];
        float xc = fminf(fmaxf(xv, -2.0f), 2.0f);
        float tv = (xc + 2.0f) * INV_H;
        int k = (int)tv;                  // tv >= 0
        k = k > NK - 1 ? NK - 1 : k;
        float u   = tv - (float)k;
        float u2  = u * u;
        float um1 = u - 1.0f;
        float c1  = u2 * (3.0f - 2.0f * u);   // h01
        float c2  = u * um1 * um1;            // h10
        float c3  = u2 * um1;                 // h11
        Rec r;
        r.off   = (i * NK + k) << 11;         // *DOUT*sizeof(Ent) = *2048 bytes
        r.w01.x = (_Float16)1.0f;
        r.w01.y = (_Float16)c1;
        r.w23.x = (_Float16)c2;
        r.w23.y = (_Float16)c3;
        r.pad   = 0;
        recs[t] = r;
    }
    __syncthreads();

    const int o = t;
    const unsigned ob = (unsigned)o * (unsigned)sizeof(Ent);
    const char* base = (const char*)C;

#pragma unroll
    for (int s = 0; s < 4; ++s) {
        float acc = 0.0f;
#pragma unroll 8
        for (int j = 0; j < ISLICE; ++j) {
            Rec r = recs[s * ISLICE + j];                   // broadcast b128
            const Ent* e = (const Ent*)(base + ((unsigned)r.off + ob));
            Ent v = *e;                                     // 8 B, L2-warm
            acc = dot2acc(v.ydy, r.w01, acc);               // y0*1 + dy*h01
            acc = dot2acc(v.hmm, r.w23, acc);               // hm0*h10 + hm1*h11
        }
        atomicAdd(&out[(chunk * 4 + s) * DOUT + o], acc);
    }
}

// ---- Merged cooperative kernel: build | grid.sync | forward ----
__global__ __launch_bounds__(256) void kan_all(const float* __restrict__ x,
                                               const float* __restrict__ y,
                                               Ent* __restrict__ C,
                                               const float* __restrict__ bias,
                                               float* __restrict__ out) {
    build_phase(y, C, bias, out);
    __threadfence();                      // release table stores device-wide
    cg::this_grid().sync();               // all 1024 blocks: table complete
    forward_phase(x, C, out);
}

// ---- Standalone fallback pair (if cooperative enqueue is rejected) ----
__global__ __launch_bounds__(256) void build_coef(const float* __restrict__ y,
                                                  Ent* __restrict__ C,
                                                  const float* __restrict__ bias,
                                                  float* __restrict__ out) {
    build_phase(y, C, bias, out);
}

__global__ __launch_bounds__(256) void kan_fwd(const float* __restrict__ x,
                                               const Ent* __restrict__ C,
                                               float* __restrict__ out) {
    forward_phase(x, C, out);
}

// ---- Fallback: no-workspace path (only if ws_size is too small) ----
__global__ __launch_bounds__(256) void kan_naive(const float* __restrict__ x,
                                                 const float* __restrict__ y,
                                                 const float* __restrict__ bias,
                                                 float* __restrict__ out) {
    __shared__ int   sk[DIN];
    __shared__ float su[DIN];

    const int b   = blockIdx.x;
    const int tid = threadIdx.x;
    const float h = HSTEP;

    {
        float xv = x[b * DIN + tid];
        float xc = fminf(fmaxf(xv, -2.0f), 2.0f);
        float t  = (xc + 2.0f) / h;
        int k = (int)floorf(t);
        k = k < 0 ? 0 : (k > NK - 1 ? NK - 1 : k);
        sk[tid] = k;
        su[tid] = t - (float)k;
    }
    __syncthreads();

    const int o = tid;
    float acc = 0.0f;
    for (int i = 0; i < DIN; ++i) {
        int   k = sk[i];
        float u = su[i];
        const float* r = y + ((size_t)i * DOUT + o) * KNOTS;
        float ym1 = r[k > 0 ? k - 1 : 0];
        float y0  = r[k];
        float y1  = r[k + 1];
        float y2  = r[k < NK - 1 ? k + 2 : KNOTS - 1];
        float dm1 = (y0 - ym1) / h;
        float d0  = (y1 - y0) / h;
        float d1  = (y2 - y1) / h;
        float mk  = (k == 0)      ? pchip_edge(d0, d1)  : pchip_inner(dm1, d0);
        float mk1 = (k == NK - 1) ? pchip_edge(d0, dm1) : pchip_inner(d0, d1);
        float hm0 = h * mk, hm1 = h * mk1;
        float dy = y1 - y0;
        float c2 = 3.0f * dy - 2.0f * hm0 - hm1;
        float c3 = hm0 + hm1 - 2.0f * dy;
        acc += fmaf(u, fmaf(u, fmaf(u, c3, c2), hm0), y0);
    }
    out[b * DOUT + o] = acc + bias[o];
}

extern "C" void kernel_launch(void* const* d_in, const int* in_sizes, int n_in,
                              void* d_out, int out_size, void* d_ws, size_t ws_size,
                              hipStream_t stream) {
    const float* x    = (const float*)d_in[0];   // (B, DIN)
    const float* y    = (const float*)d_in[1];   // (DIN, DOUT, KNOTS)
    const float* bias = (const float*)d_in[2];   // (DOUT,)
    float* out        = (float*)d_out;           // (B, DOUT)

    const size_t need = (size_t)DIN * NK * DOUT * sizeof(Ent); // ~33 MB

    if (ws_size >= need) {
        Ent* C = (Ent*)d_ws;
        void* kargs[] = { (void*)&x, (void*)&y, (void*)&C, (void*)&bias, (void*)&out };
        hipError_t e = hipLaunchCooperativeKernel((const void*)kan_all,
                                                  dim3(1024), dim3(256),
                                                  kargs, 0, stream);
        if (e != hipSuccess) {
            // enqueue rejected (capture/co-residency): proven two-kernel path
            build_coef<<<dim3(1024), dim3(256), 0, stream>>>(y, C, bias, out);
            kan_fwd<<<dim3(1024), dim3(256), 0, stream>>>(x, C, out);
        }
    } else {
        kan_naive<<<dim3(B_SZ), dim3(256), 0, stream>>>(x, y, bias, out);
    }
}

// Round 9
// 97.297 us; speedup vs baseline: 3.4591x; 3.4591x over previous
//
#include <hip/hip_runtime.h>
#include <cstdint>
#include <cstddef>

// Problem constants (from reference)
#define B_SZ   512
#define DIN    256
#define DOUT   256
#define KNOTS  64
#define NK     63                 // intervals = KNOTS-1
#define HSTEP  (4.0f / 63.0f)
#define INV_H  15.75f             // exact in f32

#define IHALF  128                // input dims per forward block (2 halves)

typedef _Float16 h2f __attribute__((ext_vector_type(2)));

// Per-interval entry: {y0, y1-y0, h*m0, h*m1} as 4 x f16 = 8 B (LDS-resident).
struct __align__(8) Ent { h2f ydy; h2f hmm; };
static_assert(sizeof(Ent) == 8, "Ent must be 8 bytes");

#if defined(__has_builtin)
#  if __has_builtin(__builtin_amdgcn_fdot2)
#    define HAVE_FDOT2 1
#  endif
#endif

static __device__ __forceinline__ float dot2acc(h2f a, h2f b, float acc) {
#ifdef HAVE_FDOT2
    return __builtin_amdgcn_fdot2(a, b, acc, false);
#else
    return acc + (float)a.x * (float)b.x + (float)a.y * (float)b.y;
#endif
}

static __device__ __forceinline__ unsigned short f16b(float v) {
    return __builtin_bit_cast(unsigned short, (_Float16)v);
}
static __device__ __forceinline__ _Float16 b16f(unsigned short v) {
    return __builtin_bit_cast(_Float16, v);
}

// ---- PCHIP slope helpers (reference semantics, f32 exact) ----
static __device__ __forceinline__ float pchip_edge(float dA, float dB) {
    float m = 0.5f * (3.0f * dA - dB);
    if (m * dA <= 0.0f) {
        m = 0.0f;
    } else if (dA * dB < 0.0f && fabsf(m) > 3.0f * fabsf(dA)) {
        m = 3.0f * dA;
    }
    return m;
}

static __device__ __forceinline__ float pchip_inner(float d0, float d1) {
    if (d0 * d1 > 0.0f) {
        float denom = d0 + d1;
        if (fabsf(denom) < 1e-12f) return 0.0f;
        return 2.0f * d0 * d1 / denom;
    }
    return 0.0f;
}

// ---- Kernel A: per-(b,i) records {k, h01, h10, h11} + out = bias ----
// W[i*512 + b], 8 B each (1 MB total, L2-resident for the forward).
// Computed exactly ONCE per (b,i) — shared by all 256 output dims.
__global__ __launch_bounds__(256) void prep_w(const float* __restrict__ x,
                                              ushort4* __restrict__ W,
                                              const float* __restrict__ bias,
                                              float* __restrict__ out) {
    const int g = blockIdx.x * 256 + threadIdx.x;   // 0..131071
    const int i = g >> 9;
    const int b = g & 511;

    float xv = x[b * DIN + i];                      // strided; L2-amortized
    float xc = fminf(fmaxf(xv, -2.0f), 2.0f);
    float tv = (xc + 2.0f) * INV_H;
    int k = (int)tv;                                // tv >= 0
    k = k > NK - 1 ? NK - 1 : k;
    float u   = tv - (float)k;
    float u2  = u * u;
    float um1 = u - 1.0f;
    float c1  = u2 * (3.0f - 2.0f * u);             // h01
    float c2  = u * um1 * um1;                      // h10
    float c3  = u2 * um1;                           // h11

    ushort4 w;
    w.x = (unsigned short)k;
    w.y = f16b(c1);
    w.z = f16b(c2);
    w.w = f16b(c3);
    W[g] = w;                                       // coalesced 8 B store

    out[g] = bias[g & (DOUT - 1)];                  // out[b'][o] = bias[o]
}

// ---- Kernel B: forward, Ent table built in LDS per (o, i-half) ----
// Grid 512 = 256 o x 2 i-halves; 512 threads = one sample b each.
// Prologue: 128 x 63 Ent entries (63 KB LDS), slopes computed once per (i,o)
// from y rows via L1/L2 (block slice = 32 KB). Main loop per term:
// coalesced 8 B W-read (L2-resident 1 MB) + ds_read_b64 + 2x fdot2.
// No global table, no scattered global gathers. 2 blocks/CU (126 KB LDS).
__global__ __launch_bounds__(512) void kan_fwd(const ushort4* __restrict__ W,
                                               const float* __restrict__ y,
                                               float* __restrict__ out) {
    __shared__ Ent ents[IHALF * NK];       // 64,512 B

    const int bid   = blockIdx.x;
    const int o     = bid >> 1;
    const int ihalf = bid & 1;
    const int t     = threadIdx.x;

    // ---- Prologue: build Ent table, 4 threads per input dim ----
    {
        const int il = t >> 2;             // 0..127
        const int q  = t & 3;              // strip
        const int k0 = q * 16;
        const int ig = ihalf * IHALF + il;
        const float* row = y + ((size_t)ig * DOUT + o) * KNOTS;

        float ys[19];                      // y[k0-1 .. k0+17], clamped
#pragma unroll
        for (int u = 0; u < 19; ++u) {
            int kk = k0 - 1 + u;
            kk = kk < 0 ? 0 : (kk > KNOTS - 1 ? KNOTS - 1 : kk);
            ys[u] = row[kk];               // scalar, L1/L2-cached
        }
        float dd[18];
#pragma unroll
        for (int u = 0; u < 18; ++u) dd[u] = (ys[u + 1] - ys[u]) * INV_H;

        const int cnt = (q == 3) ? 15 : 16;
#pragma unroll
        for (int n = 0; n < 16; ++n) {
            if (n < cnt) {
                const int k = k0 + n;
                float d_m1 = dd[n];        // d[k-1] (0-dup at k=0, overridden)
                float d_0  = dd[n + 1];    // d[k]
                float d_p1 = dd[n + 2];    // d[k+1] (0-dup at k=62, overridden)
                float mk  = pchip_inner(d_m1, d_0);
                if (k == 0)      mk  = pchip_edge(d_0, d_p1);
                float mk1 = pchip_inner(d_0, d_p1);
                if (k == NK - 1) mk1 = pchip_edge(d_0, d_m1);
                float y0 = ys[n + 1];
                float y1 = ys[n + 2];
                Ent e;
                e.ydy.x = (_Float16)y0;
                e.ydy.y = (_Float16)(y1 - y0);
                e.hmm.x = (_Float16)(HSTEP * mk);
                e.hmm.y = (_Float16)(HSTEP * mk1);
                ents[il * NK + k] = e;
            }
        }
    }
    __syncthreads();

    // ---- Main loop: one sample per thread, 128 terms ----
    const int b = t;
    const ushort4* wp = W + (size_t)(ihalf * IHALF) * 512 + b;

    float acc = 0.0f;
#pragma unroll 8
    for (int il = 0; il < IHALF; ++il) {
        ushort4 w = wp[(size_t)il * 512];           // coalesced 8 B, L2-hot
        const int k = w.x;
        Ent e = ents[il * NK + k];                  // ds_read_b64, mostly bcast
        h2f w01, w23;
        w01.x = (_Float16)1.0f;
        w01.y = b16f(w.y);
        w23.x = b16f(w.z);
        w23.y = b16f(w.w);
        acc = dot2acc(e.ydy, w01, acc);             // y0 + dy*h01
        acc = dot2acc(e.hmm, w23, acc);             // hm0*h10 + hm1*h11
    }
    atomicAdd(&out[b * DOUT + o], acc);
}

// ---- Fallback: no-workspace path (only if ws_size is too small) ----
__global__ __launch_bounds__(256) void kan_naive(const float* __restrict__ x,
                                                 const float* __restrict__ y,
                                                 const float* __restrict__ bias,
                                                 float* __restrict__ out) {
    __shared__ int   sk[DIN];
    __shared__ float su[DIN];

    const int b   = blockIdx.x;
    const int tid = threadIdx.x;
    const float h = HSTEP;

    {
        float xv = x[b * DIN + tid];
        float xc = fminf(fmaxf(xv, -2.0f), 2.0f);
        float t  = (xc + 2.0f) / h;
        int k = (int)floorf(t);
        k = k < 0 ? 0 : (k > NK - 1 ? NK - 1 : k);
        sk[tid] = k;
        su[tid] = t - (float)k;
    }
    __syncthreads();

    const int o = tid;
    float acc = 0.0f;
    for (int i = 0; i < DIN; ++i) {
        int   k = sk[i];
        float u = su[i];
        const float* r = y + ((size_t)i * DOUT + o) * KNOTS;
        float ym1 = r[k > 0 ? k - 1 : 0];
        float y0  = r[k];
        float y1  = r[k + 1];
        float y2  = r[k < NK - 1 ? k + 2 : KNOTS - 1];
        float dm1 = (y0 - ym1) / h;
        float d0  = (y1 - y0) / h;
        float d1  = (y2 - y1) / h;
        float mk  = (k == 0)      ? pchip_edge(d0, d1)  : pchip_inner(dm1, d0);
        float mk1 = (k == NK - 1) ? pchip_edge(d0, dm1) : pchip_inner(d0, d1);
        float hm0 = h * mk, hm1 = h * mk1;
        float dy = y1 - y0;
        float c2 = 3.0f * dy - 2.0f * hm0 - hm1;
        float c3 = hm0 + hm1 - 2.0f * dy;
        acc += fmaf(u, fmaf(u, fmaf(u, c3, c2), hm0), y0);
    }
    out[b * DOUT + o] = acc + bias[o];
}

extern "C" void kernel_launch(void* const* d_in, const int* in_sizes, int n_in,
                              void* d_out, int out_size, void* d_ws, size_t ws_size,
                              hipStream_t stream) {
    const float* x    = (const float*)d_in[0];   // (B, DIN)
    const float* y    = (const float*)d_in[1];   // (DIN, DOUT, KNOTS)
    const float* bias = (const float*)d_in[2];   // (DOUT,)
    float* out        = (float*)d_out;           // (B, DOUT)

    const size_t need = (size_t)DIN * B_SZ * sizeof(ushort4); // 1 MB

    if (ws_size >= need) {
        ushort4* W = (ushort4*)d_ws;
        prep_w<<<dim3((DIN * B_SZ) / 256), dim3(256), 0, stream>>>(x, W, bias, out);
        kan_fwd<<<dim3(DOUT * 2), dim3(512), 0, stream>>>(W, y, out);
    } else {
        kan_naive<<<dim3(B_SZ), dim3(256), 0, stream>>>(x, y, bias, out);
    }
}